// Round 4
// baseline (179284.509 us; speedup 1.0000x reference)
//
#include <hip/hip_runtime.h>
#include <math.h>

constexpr int NB    = 64;
constexpr int NT    = 256;
constexpr int NU    = 256;
constexpr int NMELc = 80;
constexpr int PREc  = 128;
constexpr int EMBc  = 15;
constexpr int NFc   = 128;
constexpr int ENCc  = 128;
constexpr int DECc  = 512;
constexpr int WMc   = 10;
constexpr int AKS   = 16;
constexpr int DBLK  = 512;   // decoder persistent grid
constexpr int EBLK  = 128;   // encoder persistent grid

__device__ __forceinline__ float sigm(float x) { return 1.0f / (1.0f + expf(-x)); }
__device__ __forceinline__ float softplusf(float x) { return fmaxf(x, 0.0f) + log1pf(expf(-fabsf(x))); }

// ---------------- device-scope grid barrier (all blocks resident by construction) ----------------
__device__ __forceinline__ void gbar(unsigned* cnt, unsigned* rel, unsigned e, int nblk) {
  __syncthreads();
  if (threadIdx.x == 0) {
    unsigned old = __hip_atomic_fetch_add(cnt, 1u, __ATOMIC_ACQ_REL, __HIP_MEMORY_SCOPE_AGENT);
    if (old == (unsigned)(nblk - 1)) {
      __hip_atomic_store(cnt, 0u, __ATOMIC_RELAXED, __HIP_MEMORY_SCOPE_AGENT);
      __hip_atomic_store(rel, e, __ATOMIC_RELEASE, __HIP_MEMORY_SCOPE_AGENT);
    } else {
      while (__hip_atomic_load(rel, __ATOMIC_ACQUIRE, __HIP_MEMORY_SCOPE_AGENT) < e)
        __builtin_amdgcn_s_sleep(2);
    }
  }
  __syncthreads();
}

// ---------------- generic dense ----------------
template <int K, int N, int RB>
__global__ void k_dense(const float* __restrict__ X, const float* __restrict__ W,
                        const float* __restrict__ bias, float* __restrict__ Y, int R) {
  __shared__ float xs[RB][K];
  int r0 = blockIdx.x * RB;
  int tid = threadIdx.x;  // 128
  for (int idx = tid; idx < RB * K; idx += 128) {
    int r = idx / K, k = idx % K;
    xs[r][k] = (r0 + r < R) ? X[(size_t)(r0 + r) * K + k] : 0.0f;
  }
  __syncthreads();
  int j = tid;
  if (j >= N) return;
  float acc[RB];
#pragma unroll
  for (int r = 0; r < RB; ++r) acc[r] = 0.f;
  for (int k = 0; k < K; ++k) {
    float w = W[(size_t)k * N + j];
#pragma unroll
    for (int r = 0; r < RB; ++r) acc[r] += xs[r][k] * w;
  }
  float bj = bias[j];
  for (int r = 0; r < RB; ++r)
    if (r0 + r < R) Y[(size_t)(r0 + r) * N + j] = acc[r] + bj;
}

// ---------------- embedding gather ----------------
__global__ void k_embed(const int* __restrict__ text, const float* __restrict__ emb,
                        float* __restrict__ out) {
  int idx = blockIdx.x * blockDim.x + threadIdx.x;
  if (idx >= NB * NU * EMBc) return;
  int c = idx % EMBc;
  int bu = idx / EMBc;
  int u = bu % NU, b = bu / NU;
  out[idx] = emb[text[u * NB + b] * EMBc + c];
}

// ---------------- merged conv weights ----------------
template <int CIN>
__global__ void k_weff(const float* __restrict__ w, const float* __restrict__ bb,
                       float* __restrict__ weff, float* __restrict__ beff) {
  int idx = blockIdx.x * blockDim.x + threadIdx.x;
  const int tot = 5 * CIN * NFc;
  if (idx < tot) {
    int f = idx % NFc;
    int tc = idx / NFc;
    int c = tc % CIN, t = tc / CIN;
    float m0 = (t == 2) ? 1.f : 0.f;
    float m1 = (t >= 1 && t <= 3) ? 1.f : 0.f;
    float w0 = w[((size_t)(0 * 5 + t) * CIN + c) * NFc + f];
    float w1 = w[((size_t)(1 * 5 + t) * CIN + c) * NFc + f];
    float w2 = w[((size_t)(2 * 5 + t) * CIN + c) * NFc + f];
    weff[idx] = w0 * m0 + w1 * m1 + w2;
  }
  if (idx < NFc) beff[idx] = bb[idx] + bb[NFc + idx] + bb[2 * NFc + idx];
}

// ---------------- conv stack ----------------
template <int CIN, bool RES>
__global__ void k_conv(const float* __restrict__ x, const float* __restrict__ weff,
                       const float* __restrict__ beff, float* __restrict__ y) {
  const int UT = 8;
  __shared__ float xs[(UT + 4) * CIN];
  int b = blockIdx.y, u0 = blockIdx.x * UT;
  int tid = threadIdx.x;  // 128
  for (int idx = tid; idx < (UT + 4) * CIN; idx += 128) {
    int c = idx % CIN;
    int uu = idx / CIN;
    int u = u0 + uu - 2;
    xs[idx] = (u >= 0 && u < NU) ? x[((size_t)b * NU + u) * CIN + c] : 0.f;
  }
  __syncthreads();
  int f = tid;
  float acc[UT];
#pragma unroll
  for (int r = 0; r < UT; ++r) acc[r] = beff[f];
  for (int t = 0; t < 5; ++t)
    for (int c = 0; c < CIN; ++c) {
      float w = weff[((size_t)t * CIN + c) * NFc + f];
#pragma unroll
      for (int r = 0; r < UT; ++r) acc[r] += xs[(r + t) * CIN + c] * w;
    }
  for (int r = 0; r < UT; ++r) {
    float v = fmaxf(acc[r], 0.f);
    if (RES) v += xs[(r + 2) * CIN + f];
    y[((size_t)b * NU + u0 + r) * NFc + f] = v;
  }
}

// ---------------- persistent encoder BiLSTM ----------------
struct EncP {
  const float *Wf, *bf, *Wb, *bb, *convt, *text_mask;
  float *ctx, *hbuf, *cbuf, *zE;
  unsigned *cnt, *rel;
};
__global__ __launch_bounds__(128, 2) void k_encP(EncP P) {
  const size_t ZPS = (size_t)8 * NB * 512;
  __shared__ float hs[4][128];
  __shared__ float xs[4][64];
  int tid = threadIdx.x;
  int bid = blockIdx.x;
  int d = bid >> 6;
  int q = (bid >> 4) & 3;
  int g = bid & 15;
  int b0 = g * 4;
  const float* Wd = d ? P.Wb : P.Wf;
  const float* bd = d ? P.bb : P.bf;
  int j = tid;
  unsigned ep = 0;
  for (int u = 0; u <= NU; ++u) {
    if (u > 0) {
      int ig = u - 1;
      int upos = d ? (NU - 1 - ig) : ig;
      const float* zr = P.zE + (size_t)((u - 1) & 1) * ZPS + (size_t)d * 4 * NB * 512;
      for (int bi = 0; bi < 4; ++bi) {
        int b = b0 + bi;
        float zi = bd[j], zf = bd[128 + j], zg = bd[256 + j], zo = bd[384 + j];
        for (int qq = 0; qq < 4; ++qq) {
          const float* p = zr + ((size_t)qq * NB + b) * 512;
          zi += p[j];
          zf += p[128 + j];
          zg += p[256 + j];
          zo += p[384 + j];
        }
        float cp = 0.f, hp = 0.f;
        if (u >= 2) {
          cp = P.cbuf[((size_t)(d * 2 + (u & 1)) * NB + b) * 128 + j];
          hp = P.hbuf[((size_t)(d * 2 + (u & 1)) * NB + b) * 128 + j];
        }
        float cn = sigm(zf) * cp + sigm(zi) * tanhf(zg);
        float hn = sigm(zo) * tanhf(cn);
        float mt = P.text_mask[upos * NB + b];
        hn = mt * hn + (1.f - mt) * hp;
        cn = mt * cn + (1.f - mt) * cp;
        hs[bi][j] = hn;
        if (q == 0) {
          P.hbuf[((size_t)(d * 2 + ((u - 1) & 1)) * NB + b) * 128 + j] = hn;
          P.cbuf[((size_t)(d * 2 + ((u - 1) & 1)) * NB + b) * 128 + j] = cn;
          P.ctx[((size_t)upos * NB + b) * 256 + d * 128 + j] = hn;
        }
      }
    } else {
#pragma unroll
      for (int bi = 0; bi < 4; ++bi) hs[bi][j] = 0.f;
    }
    if (u < NU) {
      __syncthreads();
      int k0 = q * 64;
      {
        int upos_x = d ? (NU - 1 - u) : u;
        for (int idx = tid; idx < 4 * 64; idx += 128) {
          int bi = idx >> 6, kk = idx & 63;
          int k = k0 + kk;
          float v = (k < 128) ? P.convt[((size_t)(b0 + bi) * NU + upos_x) * 128 + k]
                              : hs[bi][k - 128];
          xs[bi][kk] = v;
        }
      }
      __syncthreads();
      float4 acc[4];
#pragma unroll
      for (int bi = 0; bi < 4; ++bi) acc[bi] = make_float4(0.f, 0.f, 0.f, 0.f);
      const float4* Wp = (const float4*)Wd + (size_t)k0 * 128 + tid;
#pragma unroll 8
      for (int kk = 0; kk < 64; ++kk) {
        float4 w = Wp[(size_t)kk * 128];
#pragma unroll
        for (int bi = 0; bi < 4; ++bi) {
          float xv = xs[bi][kk];
          acc[bi].x += w.x * xv;
          acc[bi].y += w.y * xv;
          acc[bi].z += w.z * xv;
          acc[bi].w += w.w * xv;
        }
      }
      float4* zw = (float4*)(P.zE + (size_t)(u & 1) * ZPS) +
                   ((size_t)(d * 4 + q) * NB + b0) * 128 + tid;
#pragma unroll
      for (int bi = 0; bi < 4; ++bi) zw[(size_t)bi * 128] = acc[bi];
    }
    gbar(P.cnt, P.rel, ++ep, EBLK);
  }
}

// ---------------- persistent decoder ----------------
// Chunks: c 0..11 -> z1 (K=1408: 11x120+88), c 12..19 -> za (K=896: 8x112), c 20..31 -> z2.
// X block decode: bg = bid>>8 (32 batches each), r=bid&255, c=r>>3, nc=r&7 (256 cols).
// X(t): z2(t), z1(t+1), za(t+2).  Y(t): gate2(t), gate1(t+1), att(t+2).
struct DecP {
  const float *corr, *mel_mask, *text_mask, *ctx;
  const float *w_att, *b_att, *w_rnn1, *b_rnn1, *w_rnn2, *b_rnn2, *w_proj, *b_proj;
  float *zX, *aw, *ak, *ah, *ac, *h1, *c1, *c2, *outs, *zerob;
  unsigned *cnt, *rel;
};
__global__ __launch_bounds__(256, 2) void k_decP(DecP P) {
  __shared__ float xs[32][120];
  float* sh = &xs[0][0];
  int tid = threadIdx.x, bid = blockIdx.x;
  int bg = bid >> 8, r = bid & 255, c = r >> 3, nc = r & 7;
  int g, k0, klen;
  if (c < 12) { g = 0; k0 = c * 120; klen = (c == 11) ? 88 : 120; }
  else if (c < 20) { g = 1; k0 = (c - 12) * 112; klen = 112; }
  else { g = 2; k0 = (c - 20) * 120; klen = (c == 31) ? 88 : 120; }
  const float* Wg = (g == 0) ? P.w_rnn1 : (g == 1 ? P.w_att : P.w_rnn2);
  const float4* W4 = (const float4*)Wg;
  int bsub = tid >> 6, ct = tid & 63;
  unsigned ep = 0;
  for (int t = -2; t < NT; ++t) {
    // ================= X phase =================
    int s = (g == 0) ? (t + 1) : (g == 1 ? (t + 2) : t);
    if (s >= 0 && s < NT) {
      const float* p0 = P.corr + (size_t)s * NB * PREc;
      const int l0 = PREc;
      const float *p1, *p2, *p3;
      int s1, s2_, s3;
      if (g == 1) {  // za(s): [corr_s, aw(s-1), ah(s-1)]
        bool z = (s == 0);
        int pp = (s - 1) & 1;
        p1 = z ? P.zerob : P.aw + (size_t)pp * NB * 256; s1 = z ? 0 : 256;
        p2 = z ? P.zerob : P.ah + (size_t)pp * NB * DECc; s2_ = z ? 0 : DECc;
        p3 = P.zerob; s3 = 0;
      } else if (g == 0) {  // z1(s): [corr_s, aw(s), ah(s), h1(s-1)]
        int pp = s & 1;
        p1 = P.aw + (size_t)pp * NB * 256; s1 = 256;
        p2 = P.ah + (size_t)pp * NB * DECc; s2_ = DECc;
        bool z = (s == 0);
        p3 = z ? P.zerob : P.h1 + (size_t)((s - 1) & 1) * NB * DECc; s3 = z ? 0 : DECc;
      } else {  // z2(s): [corr_s, aw(s), h1(s), h2(s-1)]
        int pp = s & 1;
        p1 = P.aw + (size_t)pp * NB * 256; s1 = 256;
        p2 = P.h1 + (size_t)pp * NB * DECc; s2_ = DECc;
        bool z = (s == 0);
        p3 = z ? P.zerob : P.outs + (size_t)(s - 1) * NB * DECc; s3 = z ? 0 : DECc;
      }
      // stage x: 32 batches x klen rows
      for (int i2 = 0; i2 < 16; ++i2) {
        int bi = i2 * 2 + (tid >> 7);
        int kk = tid & 127;
        if (kk < klen) {
          int k = k0 + kk, b = bg * 32 + bi;
          float v;
          if (k < l0) v = p0[(size_t)b * PREc + k];
          else {
            k -= l0;
            if (k < 256) v = p1[(size_t)b * s1 + k];
            else {
              k -= 256;
              if (k < DECc) v = p2[(size_t)b * s2_ + k];
              else { k -= DECc; v = p3[(size_t)b * s3 + k]; }
            }
          }
          xs[bi][kk] = v;
        }
      }
      __syncthreads();
      float4 acc[8];
#pragma unroll
      for (int i = 0; i < 8; ++i) acc[i] = make_float4(0.f, 0.f, 0.f, 0.f);
      const float4* Wp = W4 + (size_t)k0 * 512 + nc * 64 + ct;
      int kl4 = klen >> 2;
#pragma unroll 2
      for (int k4 = 0; k4 < kl4; ++k4) {
        float4 xv[8];
#pragma unroll
        for (int bi = 0; bi < 8; ++bi) xv[bi] = *(const float4*)&xs[bsub * 8 + bi][k4 * 4];
#pragma unroll
        for (int q = 0; q < 4; ++q) {
          float4 w = Wp[(size_t)(k4 * 4 + q) * 512];
#pragma unroll
          for (int bi = 0; bi < 8; ++bi) {
            float xq = (q == 0) ? xv[bi].x : (q == 1) ? xv[bi].y : (q == 2) ? xv[bi].z : xv[bi].w;
            acc[bi].x += w.x * xq;
            acc[bi].y += w.y * xq;
            acc[bi].z += w.z * xq;
            acc[bi].w += w.w * xq;
          }
        }
      }
      float4* zp = (float4*)P.zX + ((size_t)c * 64 + bg * 32 + bsub * 8) * 512 + nc * 64 + ct;
#pragma unroll
      for (int bi = 0; bi < 8; ++bi) zp[(size_t)bi * 512] = acc[bi];
    }
    gbar(P.cnt, P.rel, ++ep, DBLK);
    // ================= Y phase =================
    if (bid < 128) {  // gate1 for step t+1
      int sg = t + 1;
      if (sg >= 0 && sg < NT) {
        int id = bid * 256 + tid, j = id & 511, b = id >> 9;
        const float* zp = P.zX + (size_t)b * 2048 + j;
        float zi = P.b_rnn1[j], zf = P.b_rnn1[512 + j], zg = P.b_rnn1[1024 + j],
              zo = P.b_rnn1[1536 + j];
        for (int cc = 0; cc < 12; ++cc) {
          const float* q = zp + (size_t)cc * 64 * 2048;
          zi += q[0]; zf += q[512]; zg += q[1024]; zo += q[1536];
        }
        bool z = (sg == 0);
        size_t po = (size_t)((sg - 1) & 1) * NB * DECc + (size_t)b * DECc + j;
        float cp = z ? 0.f : P.c1[po];
        float hp = z ? 0.f : P.h1[po];
        float cn = sigm(zf) * cp + sigm(zi) * tanhf(zg);
        float hn = sigm(zo) * tanhf(cn);
        float m = P.mel_mask[(size_t)sg * NB + b];
        size_t co = (size_t)(sg & 1) * NB * DECc + (size_t)b * DECc + j;
        P.h1[co] = m * hn + (1.f - m) * hp;
        P.c1[co] = m * cn + (1.f - m) * cp;
      }
    } else if (bid < 256) {  // gate2 for step t
      if (t >= 0) {
        int id = (bid - 128) * 256 + tid, j = id & 511, b = id >> 9;
        const float* zp = P.zX + (size_t)20 * 64 * 2048 + (size_t)b * 2048 + j;
        float zi = P.b_rnn2[j], zf = P.b_rnn2[512 + j], zg = P.b_rnn2[1024 + j],
              zo = P.b_rnn2[1536 + j];
        for (int cc = 0; cc < 12; ++cc) {
          const float* q = zp + (size_t)cc * 64 * 2048;
          zi += q[0]; zf += q[512]; zg += q[1024]; zo += q[1536];
        }
        bool z = (t == 0);
        float cp = z ? 0.f : P.c2[(size_t)((t - 1) & 1) * NB * DECc + (size_t)b * DECc + j];
        float hp = z ? 0.f : P.outs[(size_t)(t - 1) * NB * DECc + (size_t)b * DECc + j];
        float cn = sigm(zf) * cp + sigm(zi) * tanhf(zg);
        float hn = sigm(zo) * tanhf(cn);
        float m = P.mel_mask[(size_t)t * NB + b];
        P.outs[(size_t)t * NB * DECc + (size_t)b * DECc + j] = m * hn + (1.f - m) * hp;
        P.c2[(size_t)(t & 1) * NB * DECc + (size_t)b * DECc + j] = m * cn + (1.f - m) * cp;
      }
    } else if (bid < 320) {  // attention for step t+2
      int sa = t + 2;
      if (sa >= 0 && sa < NT) {
        int b = bid - 256;
        float* ah_s = sh;
        float* red_s = sh + 512;
        float* pr_s = sh + 768;
        float* abk = sh + 800;
        float* phi_s = sh + 896;
        float m = P.mel_mask[(size_t)sa * NB + b];
        bool z = (sa == 0);
        int pp = (sa - 1) & 1;
        for (int j = tid; j < 512; j += 256) {
          const float* zp = P.zX + (size_t)12 * 64 * 2048 + (size_t)b * 2048 + j;
          float zi = P.b_att[j], zf = P.b_att[512 + j], zg = P.b_att[1024 + j],
                zo = P.b_att[1536 + j];
          for (int cc = 0; cc < 8; ++cc) {
            const float* q = zp + (size_t)cc * 64 * 2048;
            zi += q[0]; zf += q[512]; zg += q[1024]; zo += q[1536];
          }
          float cp = z ? 0.f : P.ac[(size_t)pp * NB * DECc + (size_t)b * DECc + j];
          float hp = z ? 0.f : P.ah[(size_t)pp * NB * DECc + (size_t)b * DECc + j];
          float cn = sigm(zf) * cp + sigm(zi) * tanhf(zg);
          float hraw = sigm(zo) * tanhf(cn);
          ah_s[j] = hraw;
          P.ah[(size_t)(sa & 1) * NB * DECc + (size_t)b * DECc + j] = m * hraw + (1.f - m) * hp;
          P.ac[(size_t)(sa & 1) * NB * DECc + (size_t)b * DECc + j] = m * cn + (1.f - m) * cp;
        }
        __syncthreads();
        {
          int cc2 = tid & 31, ch = tid >> 5;
          float ssum = 0.f;
          if (cc2 < 30)
            for (int k = ch * 64; k < ch * 64 + 64; ++k) ssum += ah_s[k] * P.w_proj[k * 30 + cc2];
          red_s[ch * 32 + cc2] = ssum;
        }
        __syncthreads();
        if (tid < 30) {
          float ssum = P.b_proj[tid];
          for (int ch = 0; ch < 8; ++ch) ssum += red_s[ch * 32 + tid];
          pr_s[tid] = ssum;
        }
        __syncthreads();
        if (tid < WMc) {
          float kp = z ? 0.f : P.ak[(size_t)pp * NB * AKS + (size_t)b * AKS + tid];
          float a_t = softplusf(pr_s[tid]);
          float b_t = softplusf(pr_s[WMc + tid]);
          float k_t = kp + softplusf(pr_s[2 * WMc + tid]);
          abk[tid] = a_t;
          abk[32 + tid] = b_t;
          abk[64 + tid] = k_t;
          P.ak[(size_t)(sa & 1) * NB * AKS + (size_t)b * AKS + tid] = m * k_t + (1.f - m) * kp;
        }
        __syncthreads();
        {
          int u = tid;
          float ssum = 0.f;
#pragma unroll
          for (int gg = 0; gg < WMc; ++gg) {
            float dd = abk[64 + gg] - (float)u;
            ssum += abk[gg] * expf(-abk[32 + gg] * dd * dd);
          }
          phi_s[u] = ssum * P.text_mask[u * NB + b];
        }
        __syncthreads();
        {
          int dcol = tid;
          float ssum = 0.f;
#pragma unroll 8
          for (int u = 0; u < NU; ++u) ssum += phi_s[u] * P.ctx[((size_t)u * NB + b) * 256 + dcol];
          float wprev = z ? 0.f : P.aw[(size_t)pp * NB * 256 + (size_t)b * 256 + dcol];
          P.aw[(size_t)(sa & 1) * NB * 256 + (size_t)b * 256 + dcol] = m * ssum + (1.f - m) * wprev;
        }
      }
    }
    gbar(P.cnt, P.rel, ++ep, DBLK);
  }
}

// =====================================================================================
extern "C" void kernel_launch(void* const* d_in, const int* in_sizes, int n_in,
                              void* d_out, int out_size, void* d_ws, size_t ws_size,
                              hipStream_t stream) {
  const float* in_mels = (const float*)d_in[0];
  const float* mel_mask = (const float*)d_in[1];
  const int* text = (const int*)d_in[2];
  const float* text_mask = (const float*)d_in[3];
  const float* w_pre1 = (const float*)d_in[4];
  const float* b_pre1 = (const float*)d_in[5];
  const float* w_pre2 = (const float*)d_in[6];
  const float* b_pre2 = (const float*)d_in[7];
  const float* emb = (const float*)d_in[8];
  const float* conv_w0 = (const float*)d_in[9];
  const float* conv_b0 = (const float*)d_in[10];
  const float* conv_w1 = (const float*)d_in[11];
  const float* conv_b1 = (const float*)d_in[12];
  const float* conv_w2 = (const float*)d_in[13];
  const float* conv_b2 = (const float*)d_in[14];
  const float* w_bif = (const float*)d_in[15];
  const float* b_bif = (const float*)d_in[16];
  const float* w_bib = (const float*)d_in[17];
  const float* b_bib = (const float*)d_in[18];
  const float* w_att = (const float*)d_in[19];
  const float* b_att = (const float*)d_in[20];
  const float* w_proj = (const float*)d_in[21];
  const float* b_proj = (const float*)d_in[22];
  const float* w_rnn1 = (const float*)d_in[23];
  const float* b_rnn1 = (const float*)d_in[24];
  const float* w_rnn2 = (const float*)d_in[25];
  const float* b_rnn2 = (const float*)d_in[26];
  const float* w_outp = (const float*)d_in[27];
  const float* b_outp = (const float*)d_in[28];

  float* ws = (float*)d_ws;
  size_t off = 0;
  auto alloc = [&](size_t n) {
    float* p = ws + off;
    off += (n + 63) & ~(size_t)63;
    return p;
  };
  float* corr = alloc((size_t)NT * NB * PREc);
  float* embx = alloc((size_t)NB * NU * EMBc);
  float* zX = alloc((size_t)32 * NB * 2048);       // decoder partials; also conv ping / prenet tmp
  float* ctx = alloc((size_t)NU * NB * 2 * ENCc);  // also conv pong
  float* zE = alloc((size_t)2 * 8 * NB * 512);
  float* hbufE = alloc((size_t)4 * NB * ENCc);
  float* cbufE = alloc((size_t)4 * NB * ENCc);
  float* aw = alloc((size_t)2 * NB * 2 * ENCc);
  float* ak = alloc((size_t)2 * NB * AKS);
  float* ah = alloc((size_t)2 * NB * DECc);
  float* ac = alloc((size_t)2 * NB * DECc);
  float* h1 = alloc((size_t)2 * NB * DECc);
  float* c1 = alloc((size_t)2 * NB * DECc);
  float* c2 = alloc((size_t)2 * NB * DECc);
  float* outs = alloc((size_t)NT * NB * DECc);  // h2 rows; front also conv output
  float* weff0 = alloc((size_t)5 * EMBc * NFc);
  float* beff0 = alloc(NFc);
  float* weff1 = alloc((size_t)5 * NFc * NFc);
  float* beff1 = alloc(NFc);
  float* weff2 = alloc((size_t)5 * NFc * NFc);
  float* beff2 = alloc(NFc);
  float* zerob = alloc(1024);
  float* barf = alloc(64);  // barrier counters
  unsigned* bars = (unsigned*)barf;

  float* convA = zX;
  float* convB = ctx;
  float* convOut = outs;
  float* tmp = zX;

  hipMemsetAsync(zerob, 0, 1024 * sizeof(float), stream);
  hipMemsetAsync(bars, 0, 64 * sizeof(float), stream);

  // ---- prenet ----
  k_dense<NMELc, PREc, 8><<<NT * NB / 8, 128, 0, stream>>>(in_mels, w_pre1, b_pre1, tmp, NT * NB);
  k_dense<PREc, PREc, 8><<<NT * NB / 8, 128, 0, stream>>>(tmp, w_pre2, b_pre2, corr, NT * NB);

  // ---- text conv stacks: embx -> convB -> convA -> convOut ----
  k_embed<<<(NB * NU * EMBc + 255) / 256, 256, 0, stream>>>(text, emb, embx);
  k_weff<EMBc><<<(5 * EMBc * NFc + 255) / 256, 256, 0, stream>>>(conv_w0, conv_b0, weff0, beff0);
  k_weff<NFc><<<(5 * NFc * NFc + 255) / 256, 256, 0, stream>>>(conv_w1, conv_b1, weff1, beff1);
  k_weff<NFc><<<(5 * NFc * NFc + 255) / 256, 256, 0, stream>>>(conv_w2, conv_b2, weff2, beff2);
  k_conv<EMBc, false><<<dim3(NU / 8, NB), 128, 0, stream>>>(embx, weff0, beff0, convB);
  k_conv<NFc, true><<<dim3(NU / 8, NB), 128, 0, stream>>>(convB, weff1, beff1, convA);
  k_conv<NFc, true><<<dim3(NU / 8, NB), 128, 0, stream>>>(convA, weff2, beff2, convOut);

  // ---- persistent encoder ----
  {
    EncP E;
    E.Wf = w_bif; E.bf = b_bif; E.Wb = w_bib; E.bb = b_bib;
    E.convt = convOut; E.text_mask = text_mask;
    E.ctx = ctx; E.hbuf = hbufE; E.cbuf = cbufE; E.zE = zE;
    E.cnt = bars + 0; E.rel = bars + 1;
    k_encP<<<EBLK, 128, 0, stream>>>(E);
  }

  // ---- persistent decoder ----
  {
    DecP D;
    D.corr = corr; D.mel_mask = mel_mask; D.text_mask = text_mask; D.ctx = ctx;
    D.w_att = w_att; D.b_att = b_att;
    D.w_rnn1 = w_rnn1; D.b_rnn1 = b_rnn1;
    D.w_rnn2 = w_rnn2; D.b_rnn2 = b_rnn2;
    D.w_proj = w_proj; D.b_proj = b_proj;
    D.zX = zX; D.aw = aw; D.ak = ak; D.ah = ah; D.ac = ac;
    D.h1 = h1; D.c1 = c1; D.c2 = c2; D.outs = outs; D.zerob = zerob;
    D.cnt = bars + 8; D.rel = bars + 9;
    k_decP<<<DBLK, 256, 0, stream>>>(D);
  }

  // ---- output projection ----
  k_dense<DECc, NMELc, 8><<<NT * NB / 8, 128, 0, stream>>>(outs, w_outp, b_outp, (float*)d_out,
                                                           NT * NB);
}

// Round 5
// 42549.933 us; speedup vs baseline: 4.2135x; 4.2135x over previous
//
#include <hip/hip_runtime.h>
#include <math.h>

constexpr int NB    = 64;
constexpr int NT    = 256;
constexpr int NU    = 256;
constexpr int NMELc = 80;
constexpr int PREc  = 128;
constexpr int EMBc  = 15;
constexpr int NFc   = 128;
constexpr int ENCc  = 128;
constexpr int DECc  = 512;
constexpr int WMc   = 10;
constexpr int AKS   = 16;
constexpr int DBLK  = 512;   // decoder persistent grid (2 blocks/CU)
constexpr int EBLK  = 128;   // encoder persistent grid

__device__ __forceinline__ float sigm(float x) { return 1.0f / (1.0f + expf(-x)); }
__device__ __forceinline__ float softplusf(float x) { return fmaxf(x, 0.0f) + log1pf(expf(-fabsf(x))); }

// ---------------- two-level grid barrier: relaxed spin + single acquire ----------------
// c0: ngrp counters spaced 16 u32 apart (separate cachelines); c1: top counter; rel: epoch flag.
__device__ __forceinline__ void gbar(unsigned* c0, unsigned* c1, unsigned* rel, unsigned e,
                                     int grp, int grpsz, int ngrp) {
  __syncthreads();
  if (threadIdx.x == 0) {
    unsigned old = __hip_atomic_fetch_add(&c0[grp * 16], 1u, __ATOMIC_ACQ_REL,
                                          __HIP_MEMORY_SCOPE_AGENT);
    if (old == (unsigned)(grpsz - 1)) {
      __hip_atomic_store(&c0[grp * 16], 0u, __ATOMIC_RELAXED, __HIP_MEMORY_SCOPE_AGENT);
      unsigned o2 = __hip_atomic_fetch_add(c1, 1u, __ATOMIC_ACQ_REL, __HIP_MEMORY_SCOPE_AGENT);
      if (o2 == (unsigned)(ngrp - 1)) {
        __hip_atomic_store(c1, 0u, __ATOMIC_RELAXED, __HIP_MEMORY_SCOPE_AGENT);
        __hip_atomic_store(rel, e, __ATOMIC_RELEASE, __HIP_MEMORY_SCOPE_AGENT);
      } else {
        while (__hip_atomic_load(rel, __ATOMIC_RELAXED, __HIP_MEMORY_SCOPE_AGENT) < e)
          __builtin_amdgcn_s_sleep(4);
      }
    } else {
      while (__hip_atomic_load(rel, __ATOMIC_RELAXED, __HIP_MEMORY_SCOPE_AGENT) < e)
        __builtin_amdgcn_s_sleep(4);
    }
    // single acquire establishes synchronizes-with (one cache-inv per barrier, not per poll)
    (void)__hip_atomic_load(rel, __ATOMIC_ACQUIRE, __HIP_MEMORY_SCOPE_AGENT);
  }
  __syncthreads();
}

// ---------------- generic dense ----------------
template <int K, int N, int RB>
__global__ void k_dense(const float* __restrict__ X, const float* __restrict__ W,
                        const float* __restrict__ bias, float* __restrict__ Y, int R) {
  __shared__ float xs[RB][K];
  int r0 = blockIdx.x * RB;
  int tid = threadIdx.x;  // 128
  for (int idx = tid; idx < RB * K; idx += 128) {
    int r = idx / K, k = idx % K;
    xs[r][k] = (r0 + r < R) ? X[(size_t)(r0 + r) * K + k] : 0.0f;
  }
  __syncthreads();
  int j = tid;
  if (j >= N) return;
  float acc[RB];
#pragma unroll
  for (int r = 0; r < RB; ++r) acc[r] = 0.f;
  for (int k = 0; k < K; ++k) {
    float w = W[(size_t)k * N + j];
#pragma unroll
    for (int r = 0; r < RB; ++r) acc[r] += xs[r][k] * w;
  }
  float bj = bias[j];
  for (int r = 0; r < RB; ++r)
    if (r0 + r < R) Y[(size_t)(r0 + r) * N + j] = acc[r] + bj;
}

// ---------------- embedding gather ----------------
__global__ void k_embed(const int* __restrict__ text, const float* __restrict__ emb,
                        float* __restrict__ out) {
  int idx = blockIdx.x * blockDim.x + threadIdx.x;
  if (idx >= NB * NU * EMBc) return;
  int c = idx % EMBc;
  int bu = idx / EMBc;
  int u = bu % NU, b = bu / NU;
  out[idx] = emb[text[u * NB + b] * EMBc + c];
}

// ---------------- merged conv weights ----------------
template <int CIN>
__global__ void k_weff(const float* __restrict__ w, const float* __restrict__ bb,
                       float* __restrict__ weff, float* __restrict__ beff) {
  int idx = blockIdx.x * blockDim.x + threadIdx.x;
  const int tot = 5 * CIN * NFc;
  if (idx < tot) {
    int f = idx % NFc;
    int tc = idx / NFc;
    int c = tc % CIN, t = tc / CIN;
    float m0 = (t == 2) ? 1.f : 0.f;
    float m1 = (t >= 1 && t <= 3) ? 1.f : 0.f;
    float w0 = w[((size_t)(0 * 5 + t) * CIN + c) * NFc + f];
    float w1 = w[((size_t)(1 * 5 + t) * CIN + c) * NFc + f];
    float w2 = w[((size_t)(2 * 5 + t) * CIN + c) * NFc + f];
    weff[idx] = w0 * m0 + w1 * m1 + w2;
  }
  if (idx < NFc) beff[idx] = bb[idx] + bb[NFc + idx] + bb[2 * NFc + idx];
}

// ---------------- conv stack ----------------
template <int CIN, bool RES>
__global__ void k_conv(const float* __restrict__ x, const float* __restrict__ weff,
                       const float* __restrict__ beff, float* __restrict__ y) {
  const int UT = 8;
  __shared__ float xs[(UT + 4) * CIN];
  int b = blockIdx.y, u0 = blockIdx.x * UT;
  int tid = threadIdx.x;  // 128
  for (int idx = tid; idx < (UT + 4) * CIN; idx += 128) {
    int c = idx % CIN;
    int uu = idx / CIN;
    int u = u0 + uu - 2;
    xs[idx] = (u >= 0 && u < NU) ? x[((size_t)b * NU + u) * CIN + c] : 0.f;
  }
  __syncthreads();
  int f = tid;
  float acc[UT];
#pragma unroll
  for (int r = 0; r < UT; ++r) acc[r] = beff[f];
  for (int t = 0; t < 5; ++t)
    for (int c = 0; c < CIN; ++c) {
      float w = weff[((size_t)t * CIN + c) * NFc + f];
#pragma unroll
      for (int r = 0; r < UT; ++r) acc[r] += xs[(r + t) * CIN + c] * w;
    }
  for (int r = 0; r < UT; ++r) {
    float v = fmaxf(acc[r], 0.f);
    if (RES) v += xs[(r + 2) * CIN + f];
    y[((size_t)b * NU + u0 + r) * NFc + f] = v;
  }
}

// ---------------- persistent encoder BiLSTM ----------------
struct EncP {
  const float *Wf, *bf, *Wb, *bb, *convt, *text_mask;
  float *ctx, *hbuf, *cbuf, *zE;
  unsigned *c0, *c1, *rel;
};
__global__ __launch_bounds__(128, 2) void k_encP(EncP P) {
  const size_t ZPS = (size_t)8 * NB * 512;
  __shared__ float hs[4][128];
  __shared__ float xs[4][64];
  int tid = threadIdx.x;
  int bid = blockIdx.x;
  int grp = bid >> 6;  // 2 groups of 64
  int d = bid >> 6;
  int q = (bid >> 4) & 3;
  int g = bid & 15;
  int b0 = g * 4;
  const float* Wd = d ? P.Wb : P.Wf;
  const float* bd = d ? P.bb : P.bf;
  int j = tid;
  unsigned ep = 0;
  for (int u = 0; u <= NU; ++u) {
    if (u > 0) {
      int ig = u - 1;
      int upos = d ? (NU - 1 - ig) : ig;
      const float* zr = P.zE + (size_t)((u - 1) & 1) * ZPS + (size_t)d * 4 * NB * 512;
      for (int bi = 0; bi < 4; ++bi) {
        int b = b0 + bi;
        float zi = bd[j], zf = bd[128 + j], zg = bd[256 + j], zo = bd[384 + j];
        for (int qq = 0; qq < 4; ++qq) {
          const float* p = zr + ((size_t)qq * NB + b) * 512;
          zi += p[j];
          zf += p[128 + j];
          zg += p[256 + j];
          zo += p[384 + j];
        }
        float cp = 0.f, hp = 0.f;
        if (u >= 2) {
          cp = P.cbuf[((size_t)(d * 2 + (u & 1)) * NB + b) * 128 + j];
          hp = P.hbuf[((size_t)(d * 2 + (u & 1)) * NB + b) * 128 + j];
        }
        float cn = sigm(zf) * cp + sigm(zi) * tanhf(zg);
        float hn = sigm(zo) * tanhf(cn);
        float mt = P.text_mask[upos * NB + b];
        hn = mt * hn + (1.f - mt) * hp;
        cn = mt * cn + (1.f - mt) * cp;
        hs[bi][j] = hn;
        if (q == 0) {
          P.hbuf[((size_t)(d * 2 + ((u - 1) & 1)) * NB + b) * 128 + j] = hn;
          P.cbuf[((size_t)(d * 2 + ((u - 1) & 1)) * NB + b) * 128 + j] = cn;
          P.ctx[((size_t)upos * NB + b) * 256 + d * 128 + j] = hn;
        }
      }
    } else {
#pragma unroll
      for (int bi = 0; bi < 4; ++bi) hs[bi][j] = 0.f;
    }
    if (u < NU) {
      __syncthreads();
      int k0 = q * 64;
      {
        int upos_x = d ? (NU - 1 - u) : u;
        for (int idx = tid; idx < 4 * 64; idx += 128) {
          int bi = idx >> 6, kk = idx & 63;
          int k = k0 + kk;
          float v = (k < 128) ? P.convt[((size_t)(b0 + bi) * NU + upos_x) * 128 + k]
                              : hs[bi][k - 128];
          xs[bi][kk] = v;
        }
      }
      __syncthreads();
      float4 acc[4];
#pragma unroll
      for (int bi = 0; bi < 4; ++bi) acc[bi] = make_float4(0.f, 0.f, 0.f, 0.f);
      const float4* Wp = (const float4*)Wd + (size_t)k0 * 128 + tid;
#pragma unroll 8
      for (int kk = 0; kk < 64; ++kk) {
        float4 w = Wp[(size_t)kk * 128];
#pragma unroll
        for (int bi = 0; bi < 4; ++bi) {
          float xv = xs[bi][kk];
          acc[bi].x += w.x * xv;
          acc[bi].y += w.y * xv;
          acc[bi].z += w.z * xv;
          acc[bi].w += w.w * xv;
        }
      }
      float4* zw = (float4*)(P.zE + (size_t)(u & 1) * ZPS) +
                   ((size_t)(d * 4 + q) * NB + b0) * 128 + tid;
#pragma unroll
      for (int bi = 0; bi < 4; ++bi) zw[(size_t)bi * 128] = acc[bi];
    }
    gbar(P.c0, P.c1, P.rel, ++ep, grp, 64, 2);
  }
}

// ---------------- persistent decoder ----------------
// Chunks: c 0..11 -> z1 (K=1408: 11x120+88), c 12..19 -> za (K=896: 8x112), c 20..31 -> z2.
// X block decode: bg = bid>>8 (32 batches each), r=bid&255, c=r>>3, nc=r&7 (256 cols).
// X(t): z2(t), z1(t+1), za(t+2).  Y(t): gate2(t), gate1(t+1), att(t+2).
struct DecP {
  const float *corr, *mel_mask, *text_mask, *ctx;
  const float *w_att, *b_att, *w_rnn1, *b_rnn1, *w_rnn2, *b_rnn2, *w_proj, *b_proj;
  float *zX, *aw, *ak, *ah, *ac, *h1, *c1, *c2, *outs, *zerob;
  unsigned *bc0, *bc1, *brel;
};
__global__ __launch_bounds__(256, 2) void k_decP(DecP P) {
  __shared__ float xs[32][120];
  float* sh = &xs[0][0];
  int tid = threadIdx.x, bid = blockIdx.x;
  int grp = bid >> 6;  // 8 groups of 64
  int bg = bid >> 8, r = bid & 255, c = r >> 3, nc = r & 7;
  int g, k0, klen;
  if (c < 12) { g = 0; k0 = c * 120; klen = (c == 11) ? 88 : 120; }
  else if (c < 20) { g = 1; k0 = (c - 12) * 112; klen = 112; }
  else { g = 2; k0 = (c - 20) * 120; klen = (c == 31) ? 88 : 120; }
  const float* Wg = (g == 0) ? P.w_rnn1 : (g == 1 ? P.w_att : P.w_rnn2);
  const float4* W4 = (const float4*)Wg;
  int bsub = tid >> 6, ct = tid & 63;
  unsigned ep = 0;
  for (int t = -2; t < NT; ++t) {
    // ================= X phase =================
    int s = (g == 0) ? (t + 1) : (g == 1 ? (t + 2) : t);
    if (s >= 0 && s < NT) {
      const float* p0 = P.corr + (size_t)s * NB * PREc;
      const int l0 = PREc;
      const float *p1, *p2, *p3;
      int s1, s2_, s3;
      if (g == 1) {  // za(s): [corr_s, aw(s-1), ah(s-1)]
        bool z = (s == 0);
        int pp = (s - 1) & 1;
        p1 = z ? P.zerob : P.aw + (size_t)pp * NB * 256; s1 = z ? 0 : 256;
        p2 = z ? P.zerob : P.ah + (size_t)pp * NB * DECc; s2_ = z ? 0 : DECc;
        p3 = P.zerob; s3 = 0;
      } else if (g == 0) {  // z1(s): [corr_s, aw(s), ah(s), h1(s-1)]
        int pp = s & 1;
        p1 = P.aw + (size_t)pp * NB * 256; s1 = 256;
        p2 = P.ah + (size_t)pp * NB * DECc; s2_ = DECc;
        bool z = (s == 0);
        p3 = z ? P.zerob : P.h1 + (size_t)((s - 1) & 1) * NB * DECc; s3 = z ? 0 : DECc;
      } else {  // z2(s): [corr_s, aw(s), h1(s), h2(s-1)]
        int pp = s & 1;
        p1 = P.aw + (size_t)pp * NB * 256; s1 = 256;
        p2 = P.h1 + (size_t)pp * NB * DECc; s2_ = DECc;
        bool z = (s == 0);
        p3 = z ? P.zerob : P.outs + (size_t)(s - 1) * NB * DECc; s3 = z ? 0 : DECc;
      }
      // stage x: 32 batches x klen rows
      for (int i2 = 0; i2 < 16; ++i2) {
        int bi = i2 * 2 + (tid >> 7);
        int kk = tid & 127;
        if (kk < klen) {
          int k = k0 + kk, b = bg * 32 + bi;
          float v;
          if (k < l0) v = p0[(size_t)b * PREc + k];
          else {
            k -= l0;
            if (k < 256) v = p1[(size_t)b * s1 + k];
            else {
              k -= 256;
              if (k < DECc) v = p2[(size_t)b * s2_ + k];
              else { k -= DECc; v = p3[(size_t)b * s3 + k]; }
            }
          }
          xs[bi][kk] = v;
        }
      }
      __syncthreads();
      float4 acc[8];
#pragma unroll
      for (int i = 0; i < 8; ++i) acc[i] = make_float4(0.f, 0.f, 0.f, 0.f);
      const float4* Wp = W4 + (size_t)k0 * 512 + nc * 64 + ct;
      int kl4 = klen >> 2;
#pragma unroll 2
      for (int k4 = 0; k4 < kl4; ++k4) {
        float4 xv[8];
#pragma unroll
        for (int bi = 0; bi < 8; ++bi) xv[bi] = *(const float4*)&xs[bsub * 8 + bi][k4 * 4];
#pragma unroll
        for (int q = 0; q < 4; ++q) {
          float4 w = Wp[(size_t)(k4 * 4 + q) * 512];
#pragma unroll
          for (int bi = 0; bi < 8; ++bi) {
            float xq = (q == 0) ? xv[bi].x : (q == 1) ? xv[bi].y : (q == 2) ? xv[bi].z : xv[bi].w;
            acc[bi].x += w.x * xq;
            acc[bi].y += w.y * xq;
            acc[bi].z += w.z * xq;
            acc[bi].w += w.w * xq;
          }
        }
      }
      float4* zp = (float4*)P.zX + ((size_t)c * 64 + bg * 32 + bsub * 8) * 512 + nc * 64 + ct;
#pragma unroll
      for (int bi = 0; bi < 8; ++bi) zp[(size_t)bi * 512] = acc[bi];
    }
    gbar(P.bc0, P.bc1, P.brel, ++ep, grp, 64, 8);
    // ================= Y phase =================
    if (bid < 128) {  // gate1 for step t+1
      int sg = t + 1;
      if (sg >= 0 && sg < NT) {
        int id = bid * 256 + tid, j = id & 511, b = id >> 9;
        const float* zp = P.zX + (size_t)b * 2048 + j;
        float zi = P.b_rnn1[j], zf = P.b_rnn1[512 + j], zg = P.b_rnn1[1024 + j],
              zo = P.b_rnn1[1536 + j];
        for (int cc = 0; cc < 12; ++cc) {
          const float* q = zp + (size_t)cc * 64 * 2048;
          zi += q[0]; zf += q[512]; zg += q[1024]; zo += q[1536];
        }
        bool z = (sg == 0);
        size_t po = (size_t)((sg - 1) & 1) * NB * DECc + (size_t)b * DECc + j;
        float cp = z ? 0.f : P.c1[po];
        float hp = z ? 0.f : P.h1[po];
        float cn = sigm(zf) * cp + sigm(zi) * tanhf(zg);
        float hn = sigm(zo) * tanhf(cn);
        float m = P.mel_mask[(size_t)sg * NB + b];
        size_t co = (size_t)(sg & 1) * NB * DECc + (size_t)b * DECc + j;
        P.h1[co] = m * hn + (1.f - m) * hp;
        P.c1[co] = m * cn + (1.f - m) * cp;
      }
    } else if (bid < 256) {  // gate2 for step t
      if (t >= 0) {
        int id = (bid - 128) * 256 + tid, j = id & 511, b = id >> 9;
        const float* zp = P.zX + (size_t)20 * 64 * 2048 + (size_t)b * 2048 + j;
        float zi = P.b_rnn2[j], zf = P.b_rnn2[512 + j], zg = P.b_rnn2[1024 + j],
              zo = P.b_rnn2[1536 + j];
        for (int cc = 0; cc < 12; ++cc) {
          const float* q = zp + (size_t)cc * 64 * 2048;
          zi += q[0]; zf += q[512]; zg += q[1024]; zo += q[1536];
        }
        bool z = (t == 0);
        float cp = z ? 0.f : P.c2[(size_t)((t - 1) & 1) * NB * DECc + (size_t)b * DECc + j];
        float hp = z ? 0.f : P.outs[(size_t)(t - 1) * NB * DECc + (size_t)b * DECc + j];
        float cn = sigm(zf) * cp + sigm(zi) * tanhf(zg);
        float hn = sigm(zo) * tanhf(cn);
        float m = P.mel_mask[(size_t)t * NB + b];
        P.outs[(size_t)t * NB * DECc + (size_t)b * DECc + j] = m * hn + (1.f - m) * hp;
        P.c2[(size_t)(t & 1) * NB * DECc + (size_t)b * DECc + j] = m * cn + (1.f - m) * cp;
      }
    } else if (bid < 320) {  // attention for step t+2
      int sa = t + 2;
      if (sa >= 0 && sa < NT) {
        int b = bid - 256;
        float* ah_s = sh;
        float* red_s = sh + 512;
        float* pr_s = sh + 768;
        float* abk = sh + 800;
        float* phi_s = sh + 896;
        float m = P.mel_mask[(size_t)sa * NB + b];
        bool z = (sa == 0);
        int pp = (sa - 1) & 1;
        for (int j = tid; j < 512; j += 256) {
          const float* zp = P.zX + (size_t)12 * 64 * 2048 + (size_t)b * 2048 + j;
          float zi = P.b_att[j], zf = P.b_att[512 + j], zg = P.b_att[1024 + j],
                zo = P.b_att[1536 + j];
          for (int cc = 0; cc < 8; ++cc) {
            const float* q = zp + (size_t)cc * 64 * 2048;
            zi += q[0]; zf += q[512]; zg += q[1024]; zo += q[1536];
          }
          float cp = z ? 0.f : P.ac[(size_t)pp * NB * DECc + (size_t)b * DECc + j];
          float hp = z ? 0.f : P.ah[(size_t)pp * NB * DECc + (size_t)b * DECc + j];
          float cn = sigm(zf) * cp + sigm(zi) * tanhf(zg);
          float hraw = sigm(zo) * tanhf(cn);
          ah_s[j] = hraw;
          P.ah[(size_t)(sa & 1) * NB * DECc + (size_t)b * DECc + j] = m * hraw + (1.f - m) * hp;
          P.ac[(size_t)(sa & 1) * NB * DECc + (size_t)b * DECc + j] = m * cn + (1.f - m) * cp;
        }
        __syncthreads();
        {
          int cc2 = tid & 31, ch = tid >> 5;
          float ssum = 0.f;
          if (cc2 < 30)
            for (int k = ch * 64; k < ch * 64 + 64; ++k) ssum += ah_s[k] * P.w_proj[k * 30 + cc2];
          red_s[ch * 32 + cc2] = ssum;
        }
        __syncthreads();
        if (tid < 30) {
          float ssum = P.b_proj[tid];
          for (int ch = 0; ch < 8; ++ch) ssum += red_s[ch * 32 + tid];
          pr_s[tid] = ssum;
        }
        __syncthreads();
        if (tid < WMc) {
          float kp = z ? 0.f : P.ak[(size_t)pp * NB * AKS + (size_t)b * AKS + tid];
          float a_t = softplusf(pr_s[tid]);
          float b_t = softplusf(pr_s[WMc + tid]);
          float k_t = kp + softplusf(pr_s[2 * WMc + tid]);
          abk[tid] = a_t;
          abk[32 + tid] = b_t;
          abk[64 + tid] = k_t;
          P.ak[(size_t)(sa & 1) * NB * AKS + (size_t)b * AKS + tid] = m * k_t + (1.f - m) * kp;
        }
        __syncthreads();
        {
          int u = tid;
          float ssum = 0.f;
#pragma unroll
          for (int gg = 0; gg < WMc; ++gg) {
            float dd = abk[64 + gg] - (float)u;
            ssum += abk[gg] * expf(-abk[32 + gg] * dd * dd);
          }
          phi_s[u] = ssum * P.text_mask[u * NB + b];
        }
        __syncthreads();
        {
          int dcol = tid;
          float ssum = 0.f;
#pragma unroll 8
          for (int u = 0; u < NU; ++u) ssum += phi_s[u] * P.ctx[((size_t)u * NB + b) * 256 + dcol];
          float wprev = z ? 0.f : P.aw[(size_t)pp * NB * 256 + (size_t)b * 256 + dcol];
          P.aw[(size_t)(sa & 1) * NB * 256 + (size_t)b * 256 + dcol] = m * ssum + (1.f - m) * wprev;
        }
      }
    }
    gbar(P.bc0, P.bc1, P.brel, ++ep, grp, 64, 8);
  }
}

// =====================================================================================
extern "C" void kernel_launch(void* const* d_in, const int* in_sizes, int n_in,
                              void* d_out, int out_size, void* d_ws, size_t ws_size,
                              hipStream_t stream) {
  const float* in_mels = (const float*)d_in[0];
  const float* mel_mask = (const float*)d_in[1];
  const int* text = (const int*)d_in[2];
  const float* text_mask = (const float*)d_in[3];
  const float* w_pre1 = (const float*)d_in[4];
  const float* b_pre1 = (const float*)d_in[5];
  const float* w_pre2 = (const float*)d_in[6];
  const float* b_pre2 = (const float*)d_in[7];
  const float* emb = (const float*)d_in[8];
  const float* conv_w0 = (const float*)d_in[9];
  const float* conv_b0 = (const float*)d_in[10];
  const float* conv_w1 = (const float*)d_in[11];
  const float* conv_b1 = (const float*)d_in[12];
  const float* conv_w2 = (const float*)d_in[13];
  const float* conv_b2 = (const float*)d_in[14];
  const float* w_bif = (const float*)d_in[15];
  const float* b_bif = (const float*)d_in[16];
  const float* w_bib = (const float*)d_in[17];
  const float* b_bib = (const float*)d_in[18];
  const float* w_att = (const float*)d_in[19];
  const float* b_att = (const float*)d_in[20];
  const float* w_proj = (const float*)d_in[21];
  const float* b_proj = (const float*)d_in[22];
  const float* w_rnn1 = (const float*)d_in[23];
  const float* b_rnn1 = (const float*)d_in[24];
  const float* w_rnn2 = (const float*)d_in[25];
  const float* b_rnn2 = (const float*)d_in[26];
  const float* w_outp = (const float*)d_in[27];
  const float* b_outp = (const float*)d_in[28];

  float* ws = (float*)d_ws;
  size_t off = 0;
  auto alloc = [&](size_t n) {
    float* p = ws + off;
    off += (n + 63) & ~(size_t)63;
    return p;
  };
  float* corr = alloc((size_t)NT * NB * PREc);
  float* embx = alloc((size_t)NB * NU * EMBc);
  float* zX = alloc((size_t)32 * NB * 2048);       // decoder partials; also conv ping / prenet tmp
  float* ctx = alloc((size_t)NU * NB * 2 * ENCc);  // also conv pong
  float* zE = alloc((size_t)2 * 8 * NB * 512);
  float* hbufE = alloc((size_t)4 * NB * ENCc);
  float* cbufE = alloc((size_t)4 * NB * ENCc);
  float* aw = alloc((size_t)2 * NB * 2 * ENCc);
  float* ak = alloc((size_t)2 * NB * AKS);
  float* ah = alloc((size_t)2 * NB * DECc);
  float* ac = alloc((size_t)2 * NB * DECc);
  float* h1 = alloc((size_t)2 * NB * DECc);
  float* c1 = alloc((size_t)2 * NB * DECc);
  float* c2 = alloc((size_t)2 * NB * DECc);
  float* outs = alloc((size_t)NT * NB * DECc);  // h2 rows; front also conv output
  float* weff0 = alloc((size_t)5 * EMBc * NFc);
  float* beff0 = alloc(NFc);
  float* weff1 = alloc((size_t)5 * NFc * NFc);
  float* beff1 = alloc(NFc);
  float* weff2 = alloc((size_t)5 * NFc * NFc);
  float* beff2 = alloc(NFc);
  float* zerob = alloc(1024);
  float* barf = alloc(1024);  // barrier counters (4 KB)
  unsigned* bars = (unsigned*)barf;

  float* convA = zX;
  float* convB = ctx;
  float* convOut = outs;
  float* tmp = zX;

  hipMemsetAsync(zerob, 0, 1024 * sizeof(float), stream);
  hipMemsetAsync(bars, 0, 1024 * sizeof(float), stream);

  // ---- prenet ----
  k_dense<NMELc, PREc, 8><<<NT * NB / 8, 128, 0, stream>>>(in_mels, w_pre1, b_pre1, tmp, NT * NB);
  k_dense<PREc, PREc, 8><<<NT * NB / 8, 128, 0, stream>>>(tmp, w_pre2, b_pre2, corr, NT * NB);

  // ---- text conv stacks: embx -> convB -> convA -> convOut ----
  k_embed<<<(NB * NU * EMBc + 255) / 256, 256, 0, stream>>>(text, emb, embx);
  k_weff<EMBc><<<(5 * EMBc * NFc + 255) / 256, 256, 0, stream>>>(conv_w0, conv_b0, weff0, beff0);
  k_weff<NFc><<<(5 * NFc * NFc + 255) / 256, 256, 0, stream>>>(conv_w1, conv_b1, weff1, beff1);
  k_weff<NFc><<<(5 * NFc * NFc + 255) / 256, 256, 0, stream>>>(conv_w2, conv_b2, weff2, beff2);
  k_conv<EMBc, false><<<dim3(NU / 8, NB), 128, 0, stream>>>(embx, weff0, beff0, convB);
  k_conv<NFc, true><<<dim3(NU / 8, NB), 128, 0, stream>>>(convB, weff1, beff1, convA);
  k_conv<NFc, true><<<dim3(NU / 8, NB), 128, 0, stream>>>(convA, weff2, beff2, convOut);

  // ---- persistent encoder ----
  {
    EncP E;
    E.Wf = w_bif; E.bf = b_bif; E.Wb = w_bib; E.bb = b_bib;
    E.convt = convOut; E.text_mask = text_mask;
    E.ctx = ctx; E.hbuf = hbufE; E.cbuf = cbufE; E.zE = zE;
    E.c0 = bars + 256; E.c1 = bars + 320; E.rel = bars + 336;
    k_encP<<<EBLK, 128, 0, stream>>>(E);
  }

  // ---- persistent decoder ----
  {
    DecP D;
    D.corr = corr; D.mel_mask = mel_mask; D.text_mask = text_mask; D.ctx = ctx;
    D.w_att = w_att; D.b_att = b_att;
    D.w_rnn1 = w_rnn1; D.b_rnn1 = b_rnn1;
    D.w_rnn2 = w_rnn2; D.b_rnn2 = b_rnn2;
    D.w_proj = w_proj; D.b_proj = b_proj;
    D.zX = zX; D.aw = aw; D.ak = ak; D.ah = ah; D.ac = ac;
    D.h1 = h1; D.c1 = c1; D.c2 = c2; D.outs = outs; D.zerob = zerob;
    D.bc0 = bars + 0; D.bc1 = bars + 160; D.brel = bars + 176;
    k_decP<<<DBLK, 256, 0, stream>>>(D);
  }

  // ---- output projection ----
  k_dense<DECc, NMELc, 8><<<NT * NB / 8, 128, 0, stream>>>(outs, w_outp, b_outp, (float*)d_out,
                                                           NT * NB);
}

// Round 6
// 36341.714 us; speedup vs baseline: 4.9333x; 1.1708x over previous
//
#include <hip/hip_runtime.h>
#include <math.h>

constexpr int NB    = 64;
constexpr int NT    = 256;
constexpr int NU    = 256;
constexpr int NMELc = 80;
constexpr int PREc  = 128;
constexpr int EMBc  = 15;
constexpr int NFc   = 128;
constexpr int ENCc  = 128;
constexpr int DECc  = 512;
constexpr int WMc   = 10;
constexpr int AKS   = 16;
constexpr int DBLK  = 512;   // decoder persistent grid (2 blocks/CU)
constexpr int EBLK  = 128;   // encoder persistent grid

__device__ __forceinline__ float sigm(float x) { return 1.0f / (1.0f + expf(-x)); }
__device__ __forceinline__ float softplusf(float x) { return fmaxf(x, 0.0f) + log1pf(expf(-fabsf(x))); }

// ---- relaxed agent-scope (cache-bypassing, fence-free) accessors ----
__device__ __forceinline__ float ldF(const float* p) {
  return __hip_atomic_load(p, __ATOMIC_RELAXED, __HIP_MEMORY_SCOPE_AGENT);
}
__device__ __forceinline__ void stF(float* p, float v) {
  __hip_atomic_store(p, v, __ATOMIC_RELAXED, __HIP_MEMORY_SCOPE_AGENT);
}
__device__ __forceinline__ float2 ldF2(const float* p) {
  unsigned long long u = __hip_atomic_load((const unsigned long long*)p, __ATOMIC_RELAXED,
                                           __HIP_MEMORY_SCOPE_AGENT);
  return __builtin_bit_cast(float2, u);
}
__device__ __forceinline__ void stF2(float* p, float2 v) {
  __hip_atomic_store((unsigned long long*)p, __builtin_bit_cast(unsigned long long, v),
                     __ATOMIC_RELAXED, __HIP_MEMORY_SCOPE_AGENT);
}
__device__ __forceinline__ void vdrain() { asm volatile("s_waitcnt vmcnt(0)" ::: "memory"); }

// ---- two-level grid barrier: all-relaxed (NO wbl2/inv anywhere) ----
__device__ __forceinline__ void gbar(unsigned* c0, unsigned* c1, unsigned* rel, unsigned e,
                                     int grp, int grpsz, int ngrp) {
  __syncthreads();  // drains each wave's vmcnt before arrival
  if (threadIdx.x == 0) {
    unsigned old = __hip_atomic_fetch_add(&c0[grp * 16], 1u, __ATOMIC_RELAXED,
                                          __HIP_MEMORY_SCOPE_AGENT);
    if (old == (unsigned)(grpsz - 1)) {
      __hip_atomic_store(&c0[grp * 16], 0u, __ATOMIC_RELAXED, __HIP_MEMORY_SCOPE_AGENT);
      vdrain();  // reset visible before top-level arrival
      unsigned o2 = __hip_atomic_fetch_add(c1, 1u, __ATOMIC_RELAXED, __HIP_MEMORY_SCOPE_AGENT);
      if (o2 == (unsigned)(ngrp - 1)) {
        __hip_atomic_store(c1, 0u, __ATOMIC_RELAXED, __HIP_MEMORY_SCOPE_AGENT);
        vdrain();  // reset visible before release
        __hip_atomic_store(rel, e, __ATOMIC_RELAXED, __HIP_MEMORY_SCOPE_AGENT);
      } else {
        while (__hip_atomic_load(rel, __ATOMIC_RELAXED, __HIP_MEMORY_SCOPE_AGENT) < e)
          __builtin_amdgcn_s_sleep(2);
      }
    } else {
      while (__hip_atomic_load(rel, __ATOMIC_RELAXED, __HIP_MEMORY_SCOPE_AGENT) < e)
        __builtin_amdgcn_s_sleep(2);
    }
  }
  __syncthreads();
}

// ---------------- generic dense ----------------
template <int K, int N, int RB>
__global__ void k_dense(const float* __restrict__ X, const float* __restrict__ W,
                        const float* __restrict__ bias, float* __restrict__ Y, int R) {
  __shared__ float xs[RB][K];
  int r0 = blockIdx.x * RB;
  int tid = threadIdx.x;  // 128
  for (int idx = tid; idx < RB * K; idx += 128) {
    int r = idx / K, k = idx % K;
    xs[r][k] = (r0 + r < R) ? X[(size_t)(r0 + r) * K + k] : 0.0f;
  }
  __syncthreads();
  int j = tid;
  if (j >= N) return;
  float acc[RB];
#pragma unroll
  for (int r = 0; r < RB; ++r) acc[r] = 0.f;
  for (int k = 0; k < K; ++k) {
    float w = W[(size_t)k * N + j];
#pragma unroll
    for (int r = 0; r < RB; ++r) acc[r] += xs[r][k] * w;
  }
  float bj = bias[j];
  for (int r = 0; r < RB; ++r)
    if (r0 + r < R) Y[(size_t)(r0 + r) * N + j] = acc[r] + bj;
}

// ---------------- embedding gather ----------------
__global__ void k_embed(const int* __restrict__ text, const float* __restrict__ emb,
                        float* __restrict__ out) {
  int idx = blockIdx.x * blockDim.x + threadIdx.x;
  if (idx >= NB * NU * EMBc) return;
  int c = idx % EMBc;
  int bu = idx / EMBc;
  int u = bu % NU, b = bu / NU;
  out[idx] = emb[text[u * NB + b] * EMBc + c];
}

// ---------------- merged conv weights ----------------
template <int CIN>
__global__ void k_weff(const float* __restrict__ w, const float* __restrict__ bb,
                       float* __restrict__ weff, float* __restrict__ beff) {
  int idx = blockIdx.x * blockDim.x + threadIdx.x;
  const int tot = 5 * CIN * NFc;
  if (idx < tot) {
    int f = idx % NFc;
    int tc = idx / NFc;
    int c = tc % CIN, t = tc / CIN;
    float m0 = (t == 2) ? 1.f : 0.f;
    float m1 = (t >= 1 && t <= 3) ? 1.f : 0.f;
    float w0 = w[((size_t)(0 * 5 + t) * CIN + c) * NFc + f];
    float w1 = w[((size_t)(1 * 5 + t) * CIN + c) * NFc + f];
    float w2 = w[((size_t)(2 * 5 + t) * CIN + c) * NFc + f];
    weff[idx] = w0 * m0 + w1 * m1 + w2;
  }
  if (idx < NFc) beff[idx] = bb[idx] + bb[NFc + idx] + bb[2 * NFc + idx];
}

// ---------------- conv stack ----------------
template <int CIN, bool RES>
__global__ void k_conv(const float* __restrict__ x, const float* __restrict__ weff,
                       const float* __restrict__ beff, float* __restrict__ y) {
  const int UT = 8;
  __shared__ float xs[(UT + 4) * CIN];
  int b = blockIdx.y, u0 = blockIdx.x * UT;
  int tid = threadIdx.x;  // 128
  for (int idx = tid; idx < (UT + 4) * CIN; idx += 128) {
    int c = idx % CIN;
    int uu = idx / CIN;
    int u = u0 + uu - 2;
    xs[idx] = (u >= 0 && u < NU) ? x[((size_t)b * NU + u) * CIN + c] : 0.f;
  }
  __syncthreads();
  int f = tid;
  float acc[UT];
#pragma unroll
  for (int r = 0; r < UT; ++r) acc[r] = beff[f];
  for (int t = 0; t < 5; ++t)
    for (int c = 0; c < CIN; ++c) {
      float w = weff[((size_t)t * CIN + c) * NFc + f];
#pragma unroll
      for (int r = 0; r < UT; ++r) acc[r] += xs[(r + t) * CIN + c] * w;
    }
  for (int r = 0; r < UT; ++r) {
    float v = fmaxf(acc[r], 0.f);
    if (RES) v += xs[(r + 2) * CIN + f];
    y[((size_t)b * NU + u0 + r) * NFc + f] = v;
  }
}

// ---------------- persistent encoder BiLSTM ----------------
struct EncP {
  const float *Wf, *bf, *Wb, *bb, *convt, *text_mask;
  float *ctx, *hbuf, *cbuf, *zE;
  unsigned *c0, *c1, *rel;
};
__global__ __launch_bounds__(128, 2) void k_encP(EncP P) {
  const size_t ZPS = (size_t)8 * NB * 512;
  __shared__ float hs[4][128];
  __shared__ float xs[4][64];
  int tid = threadIdx.x;
  int bid = blockIdx.x;
  int grp = bid >> 6;
  int d = bid >> 6;
  int q = (bid >> 4) & 3;
  int g = bid & 15;
  int b0 = g * 4;
  const float* Wd = d ? P.Wb : P.Wf;
  const float* bd = d ? P.bb : P.bf;
  int j = tid;
  unsigned ep = 0;
  for (int u = 0; u <= NU; ++u) {
    if (u > 0) {
      int ig = u - 1;
      int upos = d ? (NU - 1 - ig) : ig;
      const float* zr = P.zE + (size_t)((u - 1) & 1) * ZPS + (size_t)d * 4 * NB * 512;
      for (int bi = 0; bi < 4; ++bi) {
        int b = b0 + bi;
        float zi = bd[j], zf = bd[128 + j], zg = bd[256 + j], zo = bd[384 + j];
        for (int qq = 0; qq < 4; ++qq) {
          const float* p = zr + ((size_t)qq * NB + b) * 512;
          zi += ldF(p + j);
          zf += ldF(p + 128 + j);
          zg += ldF(p + 256 + j);
          zo += ldF(p + 384 + j);
        }
        float cp = 0.f, hp = 0.f;
        if (u >= 2) {
          cp = ldF(P.cbuf + ((size_t)(d * 2 + (u & 1)) * NB + b) * 128 + j);
          hp = ldF(P.hbuf + ((size_t)(d * 2 + (u & 1)) * NB + b) * 128 + j);
        }
        float cn = sigm(zf) * cp + sigm(zi) * tanhf(zg);
        float hn = sigm(zo) * tanhf(cn);
        float mt = P.text_mask[upos * NB + b];
        hn = mt * hn + (1.f - mt) * hp;
        cn = mt * cn + (1.f - mt) * cp;
        hs[bi][j] = hn;
        if (q == 0) {
          stF(P.hbuf + ((size_t)(d * 2 + ((u - 1) & 1)) * NB + b) * 128 + j, hn);
          stF(P.cbuf + ((size_t)(d * 2 + ((u - 1) & 1)) * NB + b) * 128 + j, cn);
          P.ctx[((size_t)upos * NB + b) * 256 + d * 128 + j] = hn;  // consumed by next kernel
        }
      }
    } else {
#pragma unroll
      for (int bi = 0; bi < 4; ++bi) hs[bi][j] = 0.f;
    }
    if (u < NU) {
      __syncthreads();
      int k0 = q * 64;
      {
        int upos_x = d ? (NU - 1 - u) : u;
        for (int idx = tid; idx < 4 * 64; idx += 128) {
          int bi = idx >> 6, kk = idx & 63;
          int k = k0 + kk;
          float v = (k < 128) ? P.convt[((size_t)(b0 + bi) * NU + upos_x) * 128 + k]
                              : hs[bi][k - 128];
          xs[bi][kk] = v;
        }
      }
      __syncthreads();
      float4 acc[4];
#pragma unroll
      for (int bi = 0; bi < 4; ++bi) acc[bi] = make_float4(0.f, 0.f, 0.f, 0.f);
      const float4* Wp = (const float4*)Wd + (size_t)k0 * 128 + tid;
#pragma unroll 8
      for (int kk = 0; kk < 64; ++kk) {
        float4 w = Wp[(size_t)kk * 128];
#pragma unroll
        for (int bi = 0; bi < 4; ++bi) {
          float xv = xs[bi][kk];
          acc[bi].x += w.x * xv;
          acc[bi].y += w.y * xv;
          acc[bi].z += w.z * xv;
          acc[bi].w += w.w * xv;
        }
      }
      float* zwf = P.zE + (size_t)(u & 1) * ZPS + ((size_t)(d * 4 + q) * NB + b0) * 512 + tid * 4;
#pragma unroll
      for (int bi = 0; bi < 4; ++bi) {
        stF2(zwf + (size_t)bi * 512, make_float2(acc[bi].x, acc[bi].y));
        stF2(zwf + (size_t)bi * 512 + 2, make_float2(acc[bi].z, acc[bi].w));
      }
    }
    gbar(P.c0, P.c1, P.rel, ++ep, grp, 64, 2);
  }
}

// ---------------- persistent decoder ----------------
// Chunks (16): c 0..5 -> z1 (K=1408: 5x240+208), c 6..9 -> za (K=896: 4x224),
//              c 10..15 -> z2 (5x240+208).
// X block decode: bg = bid>>7 (16 batches each), r = bid&127, c = r>>3, nc = r&7.
// Same (c,nc) blocks are 128 apart (≡ mod 8 -> same XCD): weight slice L2-resident.
// X(t): z2(t), z1(t+1), za(t+2).  Y(t): gate2(t), gate1(t+1), att(t+2).
struct DecP {
  const float *corr, *mel_mask, *text_mask, *ctx;
  const float *w_att, *b_att, *w_rnn1, *b_rnn1, *w_rnn2, *b_rnn2, *w_proj, *b_proj;
  float *zX, *aw, *ak, *ah, *ac, *h1, *c1, *c2, *outs, *zerob;
  unsigned *bc0, *bc1, *brel;
};

__device__ __forceinline__ void do_gate(const float* zX, int clo, int chi, const float* bias,
                                        const float* cprev, const float* hprev, bool zfirst,
                                        const float* mm, float* hout, float* cout, int b, int j) {
  float2 zi = *(const float2*)(bias + j);
  float2 zf = *(const float2*)(bias + 512 + j);
  float2 zg = *(const float2*)(bias + 1024 + j);
  float2 zo = *(const float2*)(bias + 1536 + j);
  for (int c = clo; c <= chi; ++c) {
    const float* q = zX + ((size_t)c * NB + b) * 2048 + j;
    float2 a = ldF2(q), f2 = ldF2(q + 512), g2 = ldF2(q + 1024), o2 = ldF2(q + 1536);
    zi.x += a.x; zi.y += a.y;
    zf.x += f2.x; zf.y += f2.y;
    zg.x += g2.x; zg.y += g2.y;
    zo.x += o2.x; zo.y += o2.y;
  }
  float2 cp = zfirst ? make_float2(0.f, 0.f) : ldF2(cprev + (size_t)b * 512 + j);
  float2 hp = zfirst ? make_float2(0.f, 0.f) : ldF2(hprev + (size_t)b * 512 + j);
  float m = mm[b];
  float cnx = sigm(zf.x) * cp.x + sigm(zi.x) * tanhf(zg.x);
  float cny = sigm(zf.y) * cp.y + sigm(zi.y) * tanhf(zg.y);
  float hnx = sigm(zo.x) * tanhf(cnx);
  float hny = sigm(zo.y) * tanhf(cny);
  stF2(hout + (size_t)b * 512 + j, make_float2(m * hnx + (1.f - m) * hp.x,
                                               m * hny + (1.f - m) * hp.y));
  stF2(cout + (size_t)b * 512 + j, make_float2(m * cnx + (1.f - m) * cp.x,
                                               m * cny + (1.f - m) * cp.y));
}

__global__ __launch_bounds__(256, 2) void k_decP(DecP P) {
  __shared__ float xs[16][240];
  float* sh = &xs[0][0];
  int tid = threadIdx.x, bid = blockIdx.x;
  int grp = bid >> 6;  // 8 groups of 64
  int bg = bid >> 7, r = bid & 127, c = r >> 3, nc = r & 7;
  int g, k0, klen;
  if (c < 6)       { g = 0; k0 = c * 240;        klen = (c == 5)  ? 208 : 240; }
  else if (c < 10) { g = 1; k0 = (c - 6) * 224;  klen = 224; }
  else             { g = 2; k0 = (c - 10) * 240; klen = (c == 15) ? 208 : 240; }
  const float* Wg = (g == 0) ? P.w_rnn1 : (g == 1 ? P.w_att : P.w_rnn2);
  const float4* W4 = (const float4*)Wg;
  int bsub = tid >> 6, ct = tid & 63;
  unsigned ep = 0;
  for (int t = -2; t < NT; ++t) {
    // ================= X phase =================
    int s = (g == 0) ? (t + 1) : (g == 1 ? (t + 2) : t);
    if (s >= 0 && s < NT) {
      const float* p0 = P.corr + (size_t)s * NB * PREc;
      const float *p1, *p2, *p3;
      int s1, s2_, s3;
      if (g == 1) {  // za(s): [corr_s, aw(s-1), ah(s-1)]
        bool z = (s == 0);
        int pp = (s - 1) & 1;
        p1 = z ? P.zerob : P.aw + (size_t)pp * NB * 256; s1 = z ? 0 : 256;
        p2 = z ? P.zerob : P.ah + (size_t)pp * NB * DECc; s2_ = z ? 0 : DECc;
        p3 = P.zerob; s3 = 0;
      } else if (g == 0) {  // z1(s): [corr_s, aw(s), ah(s), h1(s-1)]
        int pp = s & 1;
        p1 = P.aw + (size_t)pp * NB * 256; s1 = 256;
        p2 = P.ah + (size_t)pp * NB * DECc; s2_ = DECc;
        bool z = (s == 0);
        p3 = z ? P.zerob : P.h1 + (size_t)((s - 1) & 1) * NB * DECc; s3 = z ? 0 : DECc;
      } else {  // z2(s): [corr_s, aw(s), h1(s), h2(s-1)]
        int pp = s & 1;
        p1 = P.aw + (size_t)pp * NB * 256; s1 = 256;
        p2 = P.h1 + (size_t)pp * NB * DECc; s2_ = DECc;
        bool z = (s == 0);
        p3 = z ? P.zerob : P.outs + (size_t)(s - 1) * NB * DECc; s3 = z ? 0 : DECc;
      }
      // stage x: 16 batches x klen rows (corr cached; state via bypass loads)
      for (int idx = tid; idx < klen * 16; idx += 256) {
        int bi = idx & 15, kk = idx >> 4;
        int k = k0 + kk, b = bg * 16 + bi;
        float v;
        if (k < PREc)
          v = p0[(size_t)b * PREc + k];
        else {
          k -= PREc;
          if (k < 256)
            v = ldF(p1 + (size_t)b * s1 + k);
          else {
            k -= 256;
            if (k < DECc)
              v = ldF(p2 + (size_t)b * s2_ + k);
            else
              v = ldF(p3 + (size_t)b * s3 + (k - DECc));
          }
        }
        xs[bi][kk] = v;
      }
      __syncthreads();
      float4 acc[4];
#pragma unroll
      for (int i = 0; i < 4; ++i) acc[i] = make_float4(0.f, 0.f, 0.f, 0.f);
      const float4* Wp = W4 + (size_t)k0 * 512 + nc * 64 + ct;
      int kl4 = klen >> 2;
#pragma unroll 2
      for (int k4 = 0; k4 < kl4; ++k4) {
        float4 xv[4];
#pragma unroll
        for (int bi = 0; bi < 4; ++bi) xv[bi] = *(const float4*)&xs[bsub * 4 + bi][k4 * 4];
#pragma unroll
        for (int q = 0; q < 4; ++q) {
          float4 w = Wp[(size_t)(k4 * 4 + q) * 512];
#pragma unroll
          for (int bi = 0; bi < 4; ++bi) {
            float xq = (q == 0) ? xv[bi].x : (q == 1) ? xv[bi].y : (q == 2) ? xv[bi].z : xv[bi].w;
            acc[bi].x += w.x * xq;
            acc[bi].y += w.y * xq;
            acc[bi].z += w.z * xq;
            acc[bi].w += w.w * xq;
          }
        }
      }
      float* zp = P.zX + ((size_t)c * NB + bg * 16 + bsub * 4) * 2048 + nc * 256 + ct * 4;
#pragma unroll
      for (int bi = 0; bi < 4; ++bi) {
        stF2(zp + (size_t)bi * 2048, make_float2(acc[bi].x, acc[bi].y));
        stF2(zp + (size_t)bi * 2048 + 2, make_float2(acc[bi].z, acc[bi].w));
      }
    }
    gbar(P.bc0, P.bc1, P.brel, ++ep, grp, 64, 8);
    // ================= Y phase =================
    if (bid < 64) {  // gate1 for step t+1 (one block per batch, 2 cols/thread)
      int sg = t + 1;
      if (sg >= 0 && sg < NT) {
        bool z = (sg == 0);
        do_gate(P.zX, 0, 5, P.b_rnn1,
                z ? P.zerob : P.c1 + (size_t)((sg - 1) & 1) * NB * 512,
                z ? P.zerob : P.h1 + (size_t)((sg - 1) & 1) * NB * 512, z,
                P.mel_mask + (size_t)sg * NB,
                P.h1 + (size_t)(sg & 1) * NB * 512,
                P.c1 + (size_t)(sg & 1) * NB * 512, bid, 2 * tid);
      }
    } else if (bid < 128) {  // gate2 for step t
      if (t >= 0) {
        bool z = (t == 0);
        do_gate(P.zX, 10, 15, P.b_rnn2,
                z ? P.zerob : P.c2 + (size_t)((t - 1) & 1) * NB * 512,
                z ? P.zerob : P.outs + (size_t)(t - 1) * NB * 512, z,
                P.mel_mask + (size_t)t * NB,
                P.outs + (size_t)t * NB * 512,
                P.c2 + (size_t)(t & 1) * NB * 512, bid - 64, 2 * tid);
      }
    } else if (bid < 192) {  // attention for step t+2 (one block per batch)
      int sa = t + 2;
      if (sa >= 0 && sa < NT) {
        int b = bid - 128;
        float* ah_s = sh;
        float* red_s = sh + 512;
        float* pr_s = sh + 768;
        float* abk = sh + 800;
        float* phi_s = sh + 896;
        float m = P.mel_mask[(size_t)sa * NB + b];
        bool z = (sa == 0);
        int pp = (sa - 1) & 1;
        {
          int j = 2 * tid;
          float2 zi = *(const float2*)(P.b_att + j);
          float2 zf = *(const float2*)(P.b_att + 512 + j);
          float2 zg = *(const float2*)(P.b_att + 1024 + j);
          float2 zo = *(const float2*)(P.b_att + 1536 + j);
          for (int cc = 6; cc <= 9; ++cc) {
            const float* q = P.zX + ((size_t)cc * NB + b) * 2048 + j;
            float2 a = ldF2(q), f2 = ldF2(q + 512), g2 = ldF2(q + 1024), o2 = ldF2(q + 1536);
            zi.x += a.x; zi.y += a.y;
            zf.x += f2.x; zf.y += f2.y;
            zg.x += g2.x; zg.y += g2.y;
            zo.x += o2.x; zo.y += o2.y;
          }
          float2 cp = z ? make_float2(0.f, 0.f)
                        : ldF2(P.ac + (size_t)pp * NB * 512 + (size_t)b * 512 + j);
          float2 hp = z ? make_float2(0.f, 0.f)
                        : ldF2(P.ah + (size_t)pp * NB * 512 + (size_t)b * 512 + j);
          float cnx = sigm(zf.x) * cp.x + sigm(zi.x) * tanhf(zg.x);
          float cny = sigm(zf.y) * cp.y + sigm(zi.y) * tanhf(zg.y);
          float hrx = sigm(zo.x) * tanhf(cnx);
          float hry = sigm(zo.y) * tanhf(cny);
          ah_s[j] = hrx;
          ah_s[j + 1] = hry;
          stF2(P.ah + (size_t)(sa & 1) * NB * 512 + (size_t)b * 512 + j,
               make_float2(m * hrx + (1.f - m) * hp.x, m * hry + (1.f - m) * hp.y));
          stF2(P.ac + (size_t)(sa & 1) * NB * 512 + (size_t)b * 512 + j,
               make_float2(m * cnx + (1.f - m) * cp.x, m * cny + (1.f - m) * cp.y));
        }
        __syncthreads();
        {
          int cc2 = tid & 31, ch = tid >> 5;
          float ssum = 0.f;
          if (cc2 < 30)
            for (int k = ch * 64; k < ch * 64 + 64; ++k) ssum += ah_s[k] * P.w_proj[k * 30 + cc2];
          red_s[ch * 32 + cc2] = ssum;
        }
        __syncthreads();
        if (tid < 30) {
          float ssum = P.b_proj[tid];
          for (int ch = 0; ch < 8; ++ch) ssum += red_s[ch * 32 + tid];
          pr_s[tid] = ssum;
        }
        __syncthreads();
        if (tid < WMc) {
          float kp = z ? 0.f : ldF(P.ak + (size_t)pp * NB * AKS + (size_t)b * AKS + tid);
          float a_t = softplusf(pr_s[tid]);
          float b_t = softplusf(pr_s[WMc + tid]);
          float k_t = kp + softplusf(pr_s[2 * WMc + tid]);
          abk[tid] = a_t;
          abk[32 + tid] = b_t;
          abk[64 + tid] = k_t;
          stF(P.ak + (size_t)(sa & 1) * NB * AKS + (size_t)b * AKS + tid,
              m * k_t + (1.f - m) * kp);
        }
        __syncthreads();
        {
          int u = tid;
          float ssum = 0.f;
#pragma unroll
          for (int gg = 0; gg < WMc; ++gg) {
            float dd = abk[64 + gg] - (float)u;
            ssum += abk[gg] * expf(-abk[32 + gg] * dd * dd);
          }
          phi_s[u] = ssum * P.text_mask[u * NB + b];
        }
        __syncthreads();
        {
          int dcol = tid;
          float ssum = 0.f;
#pragma unroll 8
          for (int u = 0; u < NU; ++u) ssum += phi_s[u] * P.ctx[((size_t)u * NB + b) * 256 + dcol];
          float wprev = z ? 0.f : ldF(P.aw + (size_t)pp * NB * 256 + (size_t)b * 256 + dcol);
          stF(P.aw + (size_t)(sa & 1) * NB * 256 + (size_t)b * 256 + dcol,
              m * ssum + (1.f - m) * wprev);
        }
      }
    }
    gbar(P.bc0, P.bc1, P.brel, ++ep, grp, 64, 8);
  }
}

// =====================================================================================
extern "C" void kernel_launch(void* const* d_in, const int* in_sizes, int n_in,
                              void* d_out, int out_size, void* d_ws, size_t ws_size,
                              hipStream_t stream) {
  const float* in_mels = (const float*)d_in[0];
  const float* mel_mask = (const float*)d_in[1];
  const int* text = (const int*)d_in[2];
  const float* text_mask = (const float*)d_in[3];
  const float* w_pre1 = (const float*)d_in[4];
  const float* b_pre1 = (const float*)d_in[5];
  const float* w_pre2 = (const float*)d_in[6];
  const float* b_pre2 = (const float*)d_in[7];
  const float* emb = (const float*)d_in[8];
  const float* conv_w0 = (const float*)d_in[9];
  const float* conv_b0 = (const float*)d_in[10];
  const float* conv_w1 = (const float*)d_in[11];
  const float* conv_b1 = (const float*)d_in[12];
  const float* conv_w2 = (const float*)d_in[13];
  const float* conv_b2 = (const float*)d_in[14];
  const float* w_bif = (const float*)d_in[15];
  const float* b_bif = (const float*)d_in[16];
  const float* w_bib = (const float*)d_in[17];
  const float* b_bib = (const float*)d_in[18];
  const float* w_att = (const float*)d_in[19];
  const float* b_att = (const float*)d_in[20];
  const float* w_proj = (const float*)d_in[21];
  const float* b_proj = (const float*)d_in[22];
  const float* w_rnn1 = (const float*)d_in[23];
  const float* b_rnn1 = (const float*)d_in[24];
  const float* w_rnn2 = (const float*)d_in[25];
  const float* b_rnn2 = (const float*)d_in[26];
  const float* w_outp = (const float*)d_in[27];
  const float* b_outp = (const float*)d_in[28];

  float* ws = (float*)d_ws;
  size_t off = 0;
  auto alloc = [&](size_t n) {
    float* p = ws + off;
    off += (n + 63) & ~(size_t)63;
    return p;
  };
  float* corr = alloc((size_t)NT * NB * PREc);
  float* embx = alloc((size_t)NB * NU * EMBc);
  float* zX = alloc((size_t)16 * NB * 2048);       // decoder partials; also conv ping / prenet tmp
  float* ctx = alloc((size_t)NU * NB * 2 * ENCc);  // also conv pong
  float* zE = alloc((size_t)2 * 8 * NB * 512);
  float* hbufE = alloc((size_t)4 * NB * ENCc);
  float* cbufE = alloc((size_t)4 * NB * ENCc);
  float* aw = alloc((size_t)2 * NB * 2 * ENCc);
  float* ak = alloc((size_t)2 * NB * AKS);
  float* ah = alloc((size_t)2 * NB * DECc);
  float* ac = alloc((size_t)2 * NB * DECc);
  float* h1 = alloc((size_t)2 * NB * DECc);
  float* c1 = alloc((size_t)2 * NB * DECc);
  float* c2 = alloc((size_t)2 * NB * DECc);
  float* outs = alloc((size_t)NT * NB * DECc);  // h2 rows; front also conv output
  float* weff0 = alloc((size_t)5 * EMBc * NFc);
  float* beff0 = alloc(NFc);
  float* weff1 = alloc((size_t)5 * NFc * NFc);
  float* beff1 = alloc(NFc);
  float* weff2 = alloc((size_t)5 * NFc * NFc);
  float* beff2 = alloc(NFc);
  float* zerob = alloc(1024);
  float* barf = alloc(1024);  // barrier counters (4 KB)
  unsigned* bars = (unsigned*)barf;

  float* convA = zX;
  float* convB = ctx;
  float* convOut = outs;
  float* tmp = zX;

  hipMemsetAsync(zerob, 0, 1024 * sizeof(float), stream);
  hipMemsetAsync(bars, 0, 1024 * sizeof(float), stream);

  // ---- prenet ----
  k_dense<NMELc, PREc, 8><<<NT * NB / 8, 128, 0, stream>>>(in_mels, w_pre1, b_pre1, tmp, NT * NB);
  k_dense<PREc, PREc, 8><<<NT * NB / 8, 128, 0, stream>>>(tmp, w_pre2, b_pre2, corr, NT * NB);

  // ---- text conv stacks: embx -> convB -> convA -> convOut ----
  k_embed<<<(NB * NU * EMBc + 255) / 256, 256, 0, stream>>>(text, emb, embx);
  k_weff<EMBc><<<(5 * EMBc * NFc + 255) / 256, 256, 0, stream>>>(conv_w0, conv_b0, weff0, beff0);
  k_weff<NFc><<<(5 * NFc * NFc + 255) / 256, 256, 0, stream>>>(conv_w1, conv_b1, weff1, beff1);
  k_weff<NFc><<<(5 * NFc * NFc + 255) / 256, 256, 0, stream>>>(conv_w2, conv_b2, weff2, beff2);
  k_conv<EMBc, false><<<dim3(NU / 8, NB), 128, 0, stream>>>(embx, weff0, beff0, convB);
  k_conv<NFc, true><<<dim3(NU / 8, NB), 128, 0, stream>>>(convB, weff1, beff1, convA);
  k_conv<NFc, true><<<dim3(NU / 8, NB), 128, 0, stream>>>(convA, weff2, beff2, convOut);

  // ---- persistent encoder ----
  {
    EncP E;
    E.Wf = w_bif; E.bf = b_bif; E.Wb = w_bib; E.bb = b_bib;
    E.convt = convOut; E.text_mask = text_mask;
    E.ctx = ctx; E.hbuf = hbufE; E.cbuf = cbufE; E.zE = zE;
    E.c0 = bars + 256; E.c1 = bars + 320; E.rel = bars + 336;
    k_encP<<<EBLK, 128, 0, stream>>>(E);
  }

  // ---- persistent decoder ----
  {
    DecP D;
    D.corr = corr; D.mel_mask = mel_mask; D.text_mask = text_mask; D.ctx = ctx;
    D.w_att = w_att; D.b_att = b_att;
    D.w_rnn1 = w_rnn1; D.b_rnn1 = b_rnn1;
    D.w_rnn2 = w_rnn2; D.b_rnn2 = b_rnn2;
    D.w_proj = w_proj; D.b_proj = b_proj;
    D.zX = zX; D.aw = aw; D.ak = ak; D.ah = ah; D.ac = ac;
    D.h1 = h1; D.c1 = c1; D.c2 = c2; D.outs = outs; D.zerob = zerob;
    D.bc0 = bars + 0; D.bc1 = bars + 160; D.brel = bars + 176;
    k_decP<<<DBLK, 256, 0, stream>>>(D);
  }

  // ---- output projection ----
  k_dense<DECc, NMELc, 8><<<NT * NB / 8, 128, 0, stream>>>(outs, w_outp, b_outp, (float*)d_out,
                                                           NT * NB);
}